// Round 1
// baseline (903.481 us; speedup 1.0000x reference)
//
#include <hip/hip_runtime.h>
#include <math.h>

#define N_NODES 40000
#define N_T0    20000
#define N_EDGES 640000
#define HDIM    128
#define NCLS    16
#define NHOPS   8

// ---------------- degree count ----------------
__global__ void deg_kernel(const int* __restrict__ src, const int* __restrict__ dst,
                           unsigned* __restrict__ out_deg, unsigned* __restrict__ in_deg, int E)
{
    int e = blockIdx.x * blockDim.x + threadIdx.x;
    if (e >= E) return;
    atomicAdd(&out_deg[src[e]], 1u);
    atomicAdd(&in_deg[dst[e]], 1u);
}

// ---------------- norms ----------------
__global__ void norm_kernel(const unsigned* __restrict__ out_deg, const unsigned* __restrict__ in_deg,
                            float* __restrict__ ns, float* __restrict__ nd, int n)
{
    int i = blockIdx.x * blockDim.x + threadIdx.x;
    if (i >= n) return;
    ns[i] = rsqrtf(fmaxf((float)out_deg[i], 1.0f));
    nd[i] = rsqrtf(fmaxf((float)in_deg[i], 1.0f));
}

// ---------------- exclusive scan of in_deg -> row_ptr (single block) ----------------
__global__ void scan_kernel(const unsigned* __restrict__ in_deg, int* __restrict__ row_ptr, int n)
{
    const int T = 1024;
    int t = threadIdx.x;
    int per = (n + T - 1) / T;
    int base = t * per;
    unsigned s = 0;
    for (int i = 0; i < per; ++i) { int idx = base + i; if (idx < n) s += in_deg[idx]; }
    __shared__ unsigned ps[T];
    ps[t] = s; __syncthreads();
    for (int off = 1; off < T; off <<= 1) {
        unsigned v = (t >= off) ? ps[t - off] : 0u;
        __syncthreads();
        ps[t] += v;
        __syncthreads();
    }
    unsigned run = ps[t] - s;   // exclusive start of this thread's chunk
    for (int i = 0; i < per; ++i) {
        int idx = base + i;
        if (idx < n) { row_ptr[idx] = (int)run; run += in_deg[idx]; }
    }
    if (t == T - 1) row_ptr[n] = (int)run;
}

// ---------------- bucket edges by dst ----------------
__global__ void bucket_kernel(const int* __restrict__ src, const int* __restrict__ dst,
                              const int* __restrict__ row_ptr, unsigned* __restrict__ cnt,
                              int* __restrict__ csr_src, int E)
{
    int e = blockIdx.x * blockDim.x + threadIdx.x;
    if (e >= E) return;
    int d = dst[e];
    unsigned p = atomicAdd(&cnt[d], 1u);
    csr_src[row_ptr[d] + (int)p] = src[e];
}

// ---------------- input projection: 8 rows per block, 128 threads ----------------
__global__ void proj_kernel(const float* __restrict__ feat, const float* __restrict__ W,
                            const float* __restrict__ b, float* __restrict__ h,
                            float* __restrict__ h_acc, int row0, int K)
{
    int j = threadIdx.x;                 // output column 0..127
    int rbase = blockIdx.x * 8;
    extern __shared__ float xs[];        // [8][K]
    for (int r = 0; r < 8; ++r)
        for (int k = j; k < K; k += 128)
            xs[r * K + k] = feat[(size_t)(rbase + r) * K + k];
    __syncthreads();
    float bj = b[j];
    float acc[8];
#pragma unroll
    for (int r = 0; r < 8; ++r) acc[r] = bj;
    for (int k = 0; k < K; ++k) {
        float w = W[k * 128 + j];
#pragma unroll
        for (int r = 0; r < 8; ++r) acc[r] += xs[r * K + k] * w;
    }
    for (int r = 0; r < 8; ++r) {
        size_t o = (size_t)(row0 + rbase + r) * 128 + j;
        h[o] = acc[r];
        h_acc[o] = acc[r];
    }
}

// ---------------- one propagation hop: 1 wave (64 lanes) per dst node ----------------
__global__ void hop_kernel(const float* __restrict__ h_cur, float* __restrict__ h_next,
                           float* __restrict__ h_acc,
                           const int* __restrict__ row_ptr, const int* __restrict__ csr_src,
                           const float* __restrict__ norm_src, const float* __restrict__ norm_dst)
{
    int node = blockIdx.x * 4 + (threadIdx.x >> 6);
    if (node >= N_NODES) return;
    int lane = threadIdx.x & 63;
    int beg = row_ptr[node], end = row_ptr[node + 1];
    float a0 = 0.f, a1 = 0.f;
    for (int e = beg; e < end; ++e) {
        int s = csr_src[e];
        float ns = norm_src[s];
        float2 v = *(const float2*)(h_cur + (size_t)s * 128 + lane * 2);
        a0 += v.x * ns;
        a1 += v.y * ns;
    }
    float nd = norm_dst[node];
    a0 *= nd; a1 *= nd;
    size_t o = (size_t)node * 128 + lane * 2;
    h_next[o]     = a0;
    h_next[o + 1] = a1;
    h_acc[o]     += a0;
    h_acc[o + 1] += a1;
}

// ---------------- finalize: /9, LN0, MLP(Wp)+ELU, LN1, head Wo, L2 row norm ----------------
__global__ void finalize_kernel(const float* __restrict__ h_acc,
                                const float* __restrict__ g0, const float* __restrict__ be0,
                                const float* __restrict__ g1, const float* __restrict__ be1,
                                const float* __restrict__ Wp, const float* __restrict__ bp,
                                const float* __restrict__ Wo, const float* __restrict__ bo,
                                float* __restrict__ out)
{
    const int RF = 8;
    int j = threadIdx.x;
    int base = blockIdx.x * RF;
    __shared__ float xs[RF][128];
    __shared__ float red[128];
    __shared__ float lg[16];
    __shared__ float rinv_s;

    float v[RF];
#pragma unroll
    for (int r = 0; r < RF; ++r) v[r] = h_acc[(size_t)(base + r) * 128 + j] * (1.0f / 9.0f);

    // LN0 per row
    for (int r = 0; r < RF; ++r) {
        float x = v[r];
        red[j] = x; __syncthreads();
        for (int s = 64; s; s >>= 1) { if (j < s) red[j] += red[j + s]; __syncthreads(); }
        float mean = red[0] * (1.f / 128.f); __syncthreads();
        float d = x - mean;
        red[j] = d * d; __syncthreads();
        for (int s = 64; s; s >>= 1) { if (j < s) red[j] += red[j + s]; __syncthreads(); }
        float var = red[0] * (1.f / 128.f); __syncthreads();
        xs[r][j] = d * rsqrtf(var + 1e-5f) * g0[j] + be0[j];
    }
    __syncthreads();

    // GEMV with Wp + ELU
    float acc[RF];
    float bj = bp[j];
#pragma unroll
    for (int r = 0; r < RF; ++r) acc[r] = bj;
    for (int k = 0; k < 128; ++k) {
        float w = Wp[k * 128 + j];
#pragma unroll
        for (int r = 0; r < RF; ++r) acc[r] += xs[r][k] * w;
    }
#pragma unroll
    for (int r = 0; r < RF; ++r) { float y = acc[r]; acc[r] = (y > 0.f) ? y : (expf(y) - 1.f); }
    __syncthreads();

    // LN1 per row
    for (int r = 0; r < RF; ++r) {
        float x = acc[r];
        red[j] = x; __syncthreads();
        for (int s = 64; s; s >>= 1) { if (j < s) red[j] += red[j + s]; __syncthreads(); }
        float mean = red[0] * (1.f / 128.f); __syncthreads();
        float d = x - mean;
        red[j] = d * d; __syncthreads();
        for (int s = 64; s; s >>= 1) { if (j < s) red[j] += red[j + s]; __syncthreads(); }
        float var = red[0] * (1.f / 128.f); __syncthreads();
        xs[r][j] = d * rsqrtf(var + 1e-5f) * g1[j] + be1[j];
    }
    __syncthreads();

    // head: 16 logits per row, then L2 normalize
    for (int r = 0; r < RF; ++r) {
        int c = j & 15, gq = j >> 4;  // 8 groups of 16 k's
        float p = 0.f;
#pragma unroll
        for (int t = 0; t < 16; ++t) {
            int k = gq * 16 + t;
            p += xs[r][k] * Wo[k * 16 + c];
        }
        red[j] = p; __syncthreads();
        if (j < 64) red[j] += red[j + 64]; __syncthreads();
        if (j < 32) red[j] += red[j + 32]; __syncthreads();
        if (j < 16) red[j] += red[j + 16]; __syncthreads();
        if (j < 16) lg[j] = red[j] + bo[j];
        __syncthreads();
        if (j == 0) {
            float ss = 0.f;
            for (int c2 = 0; c2 < 16; ++c2) ss += lg[c2] * lg[c2];
            rinv_s = 1.0f / fmaxf(sqrtf(ss), 1e-12f);
        }
        __syncthreads();
        if (j < 16) out[(size_t)(base + r) * 16 + j] = lg[j] * rinv_s;
        __syncthreads();
    }
}

// ---------------- launch ----------------
extern "C" void kernel_launch(void* const* d_in, const int* in_sizes, int n_in,
                              void* d_out, int out_size, void* d_ws, size_t ws_size,
                              hipStream_t stream)
{
    const float* feat0 = (const float*)d_in[0];
    const float* feat1 = (const float*)d_in[1];
    const int*   src   = (const int*)d_in[2];
    const int*   dst   = (const int*)d_in[3];
    const float* W0    = (const float*)d_in[4];
    const float* b0    = (const float*)d_in[5];
    const float* W1    = (const float*)d_in[6];
    const float* b1    = (const float*)d_in[7];
    const float* ln0_g = (const float*)d_in[8];
    const float* ln0_b = (const float*)d_in[9];
    const float* ln1_g = (const float*)d_in[10];
    const float* ln1_b = (const float*)d_in[11];
    const float* Wp    = (const float*)d_in[12];
    const float* bp    = (const float*)d_in[13];
    const float* Wo    = (const float*)d_in[14];
    const float* bo    = (const float*)d_in[15];
    float* out = (float*)d_out;

    char* ws = (char*)d_ws;
    // workspace layout (bytes)
    float*    h0      = (float*)(ws + 0);            // 40000*128*4 = 20,480,000
    float*    h1      = (float*)(ws + 20480000);     // 20,480,000
    float*    hacc    = (float*)(ws + 40960000);     // 20,480,000
    float*    nsrc    = (float*)(ws + 61440000);     // 160,000
    float*    ndst    = (float*)(ws + 61600000);     // 160,000
    unsigned* odeg    = (unsigned*)(ws + 61760000);  // 160,000
    unsigned* ideg    = (unsigned*)(ws + 61920000);  // 160,000
    unsigned* cnt     = (unsigned*)(ws + 62080000);  // 160,000
    int*      row_ptr = (int*)(ws + 62240000);       // 160,256 (padded)
    int*      csr     = (int*)(ws + 62400256);       // 2,560,000
    // total ~64.96 MB

    // zero degree counters + bucket counters (contiguous 480000 bytes)
    hipMemsetAsync(odeg, 0, 480000, stream);

    // degrees
    deg_kernel<<<(N_EDGES + 255) / 256, 256, 0, stream>>>(src, dst, odeg, ideg, N_EDGES);
    // norms
    norm_kernel<<<(N_NODES + 255) / 256, 256, 0, stream>>>(odeg, ideg, nsrc, ndst, N_NODES);
    // row_ptr scan
    scan_kernel<<<1, 1024, 0, stream>>>(ideg, row_ptr, N_NODES);
    // bucket
    bucket_kernel<<<(N_EDGES + 255) / 256, 256, 0, stream>>>(src, dst, row_ptr, cnt, csr, N_EDGES);

    // projections -> h0 (and h_acc init)
    proj_kernel<<<N_T0 / 8, 128, 8 * 256 * 4, stream>>>(feat0, W0, b0, h0, hacc, 0, 256);
    proj_kernel<<<N_T0 / 8, 128, 8 * 128 * 4, stream>>>(feat1, W1, b1, h0, hacc, N_T0, 128);

    // 8 hops with pointer double-buffering
    float* cur = h0;
    float* nxt = h1;
    for (int h = 0; h < NHOPS; ++h) {
        hop_kernel<<<N_NODES / 4, 256, 0, stream>>>(cur, nxt, hacc, row_ptr, csr, nsrc, ndst);
        float* t = cur; cur = nxt; nxt = t;
    }

    // finalize
    finalize_kernel<<<N_NODES / 8, 128, 0, stream>>>(hacc, ln0_g, ln0_b, ln1_g, ln1_b,
                                                     Wp, bp, Wo, bo, out);
}

// Round 3
// 674.712 us; speedup vs baseline: 1.3391x; 1.3391x over previous
//
#include <hip/hip_runtime.h>
#include <hip/hip_fp16.h>
#include <math.h>

#define N_NODES 40000
#define N_T0    20000
#define N_EDGES 640000
#define HDIM    128
#define NHOPS   8

// ---------------- degree count ----------------
__global__ void deg_kernel(const int* __restrict__ src, const int* __restrict__ dst,
                           unsigned* __restrict__ out_deg, unsigned* __restrict__ in_deg, int E)
{
    int e = blockIdx.x * blockDim.x + threadIdx.x;
    if (e >= E) return;
    atomicAdd(&out_deg[src[e]], 1u);
    atomicAdd(&in_deg[dst[e]], 1u);
}

// ---------------- norms: ns (src scale), nd (dst scale), nsd = nd*ns ----------------
__global__ void norm_kernel(const unsigned* __restrict__ out_deg, const unsigned* __restrict__ in_deg,
                            float* __restrict__ ns, float* __restrict__ nd,
                            float* __restrict__ nsd, int n)
{
    int i = blockIdx.x * blockDim.x + threadIdx.x;
    if (i >= n) return;
    float s = rsqrtf(fmaxf((float)out_deg[i], 1.0f));
    float d = rsqrtf(fmaxf((float)in_deg[i], 1.0f));
    ns[i] = s; nd[i] = d; nsd[i] = s * d;
}

// ---------------- exclusive scan of in_deg -> row_ptr (single block) ----------------
__global__ void scan_kernel(const unsigned* __restrict__ in_deg, int* __restrict__ row_ptr, int n)
{
    const int T = 1024;
    int t = threadIdx.x;
    int per = (n + T - 1) / T;
    int base = t * per;
    unsigned s = 0;
    for (int i = 0; i < per; ++i) { int idx = base + i; if (idx < n) s += in_deg[idx]; }
    __shared__ unsigned ps[T];
    ps[t] = s; __syncthreads();
    for (int off = 1; off < T; off <<= 1) {
        unsigned v = (t >= off) ? ps[t - off] : 0u;
        __syncthreads();
        ps[t] += v;
        __syncthreads();
    }
    unsigned run = ps[t] - s;
    for (int i = 0; i < per; ++i) {
        int idx = base + i;
        if (idx < n) { row_ptr[idx] = (int)run; run += in_deg[idx]; }
    }
    if (t == T - 1) row_ptr[n] = (int)run;
}

// ---------------- bucket edges by dst ----------------
__global__ void bucket_kernel(const int* __restrict__ src, const int* __restrict__ dst,
                              const int* __restrict__ row_ptr, unsigned* __restrict__ cnt,
                              int* __restrict__ csr_src, int E)
{
    int e = blockIdx.x * blockDim.x + threadIdx.x;
    if (e >= E) return;
    int d = dst[e];
    unsigned p = atomicAdd(&cnt[d], 1u);
    csr_src[row_ptr[d] + (int)p] = src[e];
}

// ---------------- input projection: hacc (f32) + g = h*ns (fp16) ----------------
__global__ void proj_kernel(const float* __restrict__ feat, const float* __restrict__ W,
                            const float* __restrict__ b, const float* __restrict__ ns,
                            float* __restrict__ hacc, __half* __restrict__ g,
                            int row0, int K)
{
    int j = threadIdx.x;                 // output column 0..127
    int rbase = blockIdx.x * 8;
    extern __shared__ float xs[];        // [8][K]
    for (int r = 0; r < 8; ++r)
        for (int k = j; k < K; k += 128)
            xs[r * K + k] = feat[(size_t)(rbase + r) * K + k];
    __syncthreads();
    float bj = b[j];
    float acc[8];
#pragma unroll
    for (int r = 0; r < 8; ++r) acc[r] = bj;
    for (int k = 0; k < K; ++k) {
        float w = W[k * 128 + j];
#pragma unroll
        for (int r = 0; r < 8; ++r) acc[r] += xs[r * K + k] * w;
    }
    for (int r = 0; r < 8; ++r) {
        int row = row0 + rbase + r;
        size_t o = (size_t)row * 128 + j;
        hacc[o] = acc[r];
        g[o] = __float2half(acc[r] * ns[row]);
    }
}

// ---------------- propagation hop: 1 wave per dst node; FINAL fuses the MLP head ----------------
template<bool FINAL>
__global__ void hop_kernel(const __half* __restrict__ g_cur,
                           __half* __restrict__ g_next,
                           float* __restrict__ hacc,
                           const int* __restrict__ row_ptr, const int* __restrict__ csr,
                           const float* __restrict__ nd, const float* __restrict__ nsd,
                           const float* __restrict__ ln0g, const float* __restrict__ ln0b,
                           const float* __restrict__ ln1g, const float* __restrict__ ln1b,
                           const float* __restrict__ Wp, const float* __restrict__ bp,
                           const float* __restrict__ Wo, const float* __restrict__ bo,
                           float* __restrict__ out)
{
    int node = blockIdx.x * 4 + (threadIdx.x >> 6);
    int lane = threadIdx.x & 63;
    int beg = row_ptr[node], end = row_ptr[node + 1];

    float a0 = 0.f, a1 = 0.f;
    int e = beg;
    for (; e + 4 <= end; e += 4) {
        int s0 = csr[e], s1 = csr[e + 1], s2 = csr[e + 2], s3 = csr[e + 3];
        __half2 v0 = *(const __half2*)(g_cur + ((size_t)s0 << 7) + (lane << 1));
        __half2 v1 = *(const __half2*)(g_cur + ((size_t)s1 << 7) + (lane << 1));
        __half2 v2 = *(const __half2*)(g_cur + ((size_t)s2 << 7) + (lane << 1));
        __half2 v3 = *(const __half2*)(g_cur + ((size_t)s3 << 7) + (lane << 1));
        float2 f0 = __half22float2(v0), f1 = __half22float2(v1);
        float2 f2 = __half22float2(v2), f3 = __half22float2(v3);
        a0 += (f0.x + f1.x) + (f2.x + f3.x);
        a1 += (f0.y + f1.y) + (f2.y + f3.y);
    }
    for (; e < end; ++e) {
        int s = csr[e];
        float2 f = __half22float2(*(const __half2*)(g_cur + ((size_t)s << 7) + (lane << 1)));
        a0 += f.x; a1 += f.y;
    }

    float ndv = nd[node];
    float h0 = a0 * ndv, h1 = a1 * ndv;   // h_new = nd * sum(g)
    size_t o = ((size_t)node << 7) + (lane << 1);

    if (!FINAL) {
        float2 acc = *(const float2*)(hacc + o);
        acc.x += h0; acc.y += h1;
        *(float2*)(hacc + o) = acc;
        // g_next = h_new * ns = a * (nd*ns) = a * nsd   (NOT h0*nsd — that double-counts nd)
        float nsdv = nsd[node];
        *(__half2*)(g_next + o) = __float22half2_rn(make_float2(a0 * nsdv, a1 * nsdv));
        return;
    }

    // ----- fused finalize: x = (hacc + h)/9 -> LN0 -> Wp+ELU -> LN1 -> Wo -> L2 norm -----
    float2 ha = *(const float2*)(hacc + o);
    float x0 = (ha.x + h0) * (1.0f / 9.0f);
    float x1 = (ha.y + h1) * (1.0f / 9.0f);

    // LN0 (wave-level shfl reductions; 64 lanes x 2 channels = 128)
    float s = x0 + x1;
#pragma unroll
    for (int m = 32; m; m >>= 1) s += __shfl_xor(s, m);
    float mean = s * (1.0f / 128.0f);
    float d0 = x0 - mean, d1 = x1 - mean;
    float q = d0 * d0 + d1 * d1;
#pragma unroll
    for (int m = 32; m; m >>= 1) q += __shfl_xor(q, m);
    float rstd = rsqrtf(q * (1.0f / 128.0f) + 1e-5f);
    int c0 = lane << 1, c1 = c0 + 1;
    float xn0 = d0 * rstd * ln0g[c0] + ln0b[c0];
    float xn1 = d1 * rstd * ln0g[c1] + ln0b[c1];

    // GEMV Wp: this lane owns output columns c0, c1
    float ax = bp[c0], ay = bp[c1];
#pragma unroll
    for (int k = 0; k < 128; ++k) {
        float xk = __shfl((k & 1) ? xn1 : xn0, k >> 1);
        float2 w = *(const float2*)(Wp + k * 128 + c0);
        ax += xk * w.x; ay += xk * w.y;
    }
    // ELU
    ax = ax > 0.f ? ax : (expf(ax) - 1.f);
    ay = ay > 0.f ? ay : (expf(ay) - 1.f);

    // LN1
    s = ax + ay;
#pragma unroll
    for (int m = 32; m; m >>= 1) s += __shfl_xor(s, m);
    mean = s * (1.0f / 128.0f);
    d0 = ax - mean; d1 = ay - mean;
    q = d0 * d0 + d1 * d1;
#pragma unroll
    for (int m = 32; m; m >>= 1) q += __shfl_xor(q, m);
    rstd = rsqrtf(q * (1.0f / 128.0f) + 1e-5f);
    float y0 = d0 * rstd * ln1g[c0] + ln1b[c0];
    float y1 = d1 * rstd * ln1g[c1] + ln1b[c1];

    // head: per-lane partials into 16 logits, butterfly-reduce
    float p[16];
    const float* w0 = Wo + c0 * 16;
    const float* w1 = Wo + c1 * 16;
#pragma unroll
    for (int c = 0; c < 16; ++c) p[c] = y0 * w0[c] + y1 * w1[c];
#pragma unroll
    for (int m = 32; m; m >>= 1) {
#pragma unroll
        for (int c = 0; c < 16; ++c) p[c] += __shfl_xor(p[c], m);
    }

    if (lane == 0) {
        float ss = 0.f;
#pragma unroll
        for (int c = 0; c < 16; ++c) { p[c] += bo[c]; ss += p[c] * p[c]; }
        float rinv = 1.0f / fmaxf(sqrtf(ss), 1e-12f);
        float4* op = (float4*)(out + (size_t)node * 16);
        op[0] = make_float4(p[0] * rinv, p[1] * rinv, p[2] * rinv, p[3] * rinv);
        op[1] = make_float4(p[4] * rinv, p[5] * rinv, p[6] * rinv, p[7] * rinv);
        op[2] = make_float4(p[8] * rinv, p[9] * rinv, p[10] * rinv, p[11] * rinv);
        op[3] = make_float4(p[12] * rinv, p[13] * rinv, p[14] * rinv, p[15] * rinv);
    }
}

// ---------------- launch ----------------
extern "C" void kernel_launch(void* const* d_in, const int* in_sizes, int n_in,
                              void* d_out, int out_size, void* d_ws, size_t ws_size,
                              hipStream_t stream)
{
    const float* feat0 = (const float*)d_in[0];
    const float* feat1 = (const float*)d_in[1];
    const int*   src   = (const int*)d_in[2];
    const int*   dst   = (const int*)d_in[3];
    const float* W0    = (const float*)d_in[4];
    const float* b0    = (const float*)d_in[5];
    const float* W1    = (const float*)d_in[6];
    const float* b1    = (const float*)d_in[7];
    const float* ln0_g = (const float*)d_in[8];
    const float* ln0_b = (const float*)d_in[9];
    const float* ln1_g = (const float*)d_in[10];
    const float* ln1_b = (const float*)d_in[11];
    const float* Wp    = (const float*)d_in[12];
    const float* bp    = (const float*)d_in[13];
    const float* Wo    = (const float*)d_in[14];
    const float* bo    = (const float*)d_in[15];
    float* out = (float*)d_out;

    char* ws = (char*)d_ws;
    // workspace layout (bytes)
    float*    hacc    = (float*)(ws + 0);            // 40000*128*4 = 20,480,000
    __half*   gA      = (__half*)(ws + 20480000);    // 10,240,000
    __half*   gB      = (__half*)(ws + 30720000);    // 10,240,000
    float*    nsrc    = (float*)(ws + 40960000);     // 160,000
    float*    ndst    = (float*)(ws + 41120000);     // 160,000
    float*    nsd     = (float*)(ws + 41280000);     // 160,000
    unsigned* odeg    = (unsigned*)(ws + 41440000);  // 160,000
    unsigned* ideg    = (unsigned*)(ws + 41600000);  // 160,000
    unsigned* cnt     = (unsigned*)(ws + 41760000);  // 160,000
    int*      row_ptr = (int*)(ws + 41920000);       // 160,256 (padded)
    int*      csr     = (int*)(ws + 42080256);       // 2,560,000
    // total ~44.6 MB

    // zero degree + bucket counters (contiguous: odeg, ideg, cnt)
    hipMemsetAsync(odeg, 0, 480000, stream);

    deg_kernel<<<(N_EDGES + 255) / 256, 256, 0, stream>>>(src, dst, odeg, ideg, N_EDGES);
    norm_kernel<<<(N_NODES + 255) / 256, 256, 0, stream>>>(odeg, ideg, nsrc, ndst, nsd, N_NODES);
    scan_kernel<<<1, 1024, 0, stream>>>(ideg, row_ptr, N_NODES);
    bucket_kernel<<<(N_EDGES + 255) / 256, 256, 0, stream>>>(src, dst, row_ptr, cnt, csr, N_EDGES);

    proj_kernel<<<N_T0 / 8, 128, 8 * 256 * 4, stream>>>(feat0, W0, b0, nsrc, hacc, gA, 0, 256);
    proj_kernel<<<N_T0 / 8, 128, 8 * 128 * 4, stream>>>(feat1, W1, b1, nsrc, hacc, gA, N_T0, 128);

    // hops 1..7: normal; hop 8: fused finalize
    __half* cur = gA;
    __half* nxt = gB;
    for (int h = 0; h < NHOPS - 1; ++h) {
        hop_kernel<false><<<N_NODES / 4, 256, 0, stream>>>(cur, nxt, hacc, row_ptr, csr,
                                                           ndst, nsd,
                                                           ln0_g, ln0_b, ln1_g, ln1_b,
                                                           Wp, bp, Wo, bo, out);
        __half* t = cur; cur = nxt; nxt = t;
    }
    hop_kernel<true><<<N_NODES / 4, 256, 0, stream>>>(cur, nullptr, hacc, row_ptr, csr,
                                                      ndst, nsd,
                                                      ln0_g, ln0_b, ln1_g, ln1_b,
                                                      Wp, bp, Wo, bo, out);
}